// Round 11
// baseline (265.914 us; speedup 1.0000x reference)
//
#include <hip/hip_runtime.h>

#define T_ 512
#define K_ 128
#define L2E 1.4426950408889634f
#define LN2 0.6931471805599453f

typedef _Float16 hv2 __attribute__((ext_vector_type(2)));

__device__ __forceinline__ int irl(int v, int lane) {
    return __builtin_amdgcn_readlane(v, lane);
}
__device__ __forceinline__ hv2 as_hv2(int i) { return __builtin_bit_cast(hv2, i); }
__device__ __forceinline__ hv2 pkh(float a, float b) {
    return __builtin_bit_cast(hv2, __builtin_amdgcn_cvt_pkrtz(a, b));
}
__device__ __forceinline__ int pk16(float a, float b) {
    return __builtin_bit_cast(int, __builtin_amdgcn_cvt_pkrtz(a, b));
}

#if __has_builtin(__builtin_amdgcn_fdot2)
#define FDOT2(a, b, c) __builtin_amdgcn_fdot2((a), (b), (c), false)
#else
__device__ __forceinline__ float fdot2_emu(hv2 a, hv2 b, float c) {
    return fmaf((float)a.x, (float)b.x, fmaf((float)a.y, (float)b.y, c));
}
#define FDOT2(a, b, c) fdot2_emu((a), (b), (c))
#endif

// wave64 max-reduce step via DPP (pure VALU). values >= 0 so 0-fill safe.
#define DPPMAX(m, ctrl)                                                     \
    m = fmaxf(m, __int_as_float(__builtin_amdgcn_update_dpp(                 \
                     0, __float_as_int(m), (ctrl), 0xf, 0xf, true)))

// One step. SLOT = h slot being refilled (read 4 bodies later); SNEXT = h for
// step tt+1 (lag-1 ehc build). Matvec: 8 groups of {stage 8 readlanes ->
// 16 fdot2 consuming the PREVIOUS group's SGPRs}; sched_barrier(0) pins the
// order so every readlane result is consumed >=16 instrs later (no
// VALU->SGPR->VALU hazard bubbles on the critical path).
#define BODY(tt, SLOT, SNEXT)                                                \
    {                                                                        \
        const int tc = ((tt) + 4 < len) ? (tt) + 4 : len - 1;                \
        SLOT = hb[(size_t)tc * 64];                                          \
        float Aacc[8] = {0,0,0,0,0,0,0,0};                                   \
        float Bacc[8] = {0,0,0,0,0,0,0,0};                                   \
        int sb[2][8];                                                        \
        _Pragma("unroll")                                                    \
        for (int d = 0; d < 8; ++d) sb[0][d] = irl(wpk, d);                  \
        __builtin_amdgcn_sched_barrier(0);                                   \
        _Pragma("unroll")                                                    \
        for (int grp = 0; grp < 8; ++grp) {                                  \
            const int cur = grp & 1;                                         \
            if (grp < 7) {                                                   \
                _Pragma("unroll")                                            \
                for (int d = 0; d < 8; ++d)                                  \
                    sb[cur ^ 1][d] = irl(wpk, 8 * (grp + 1) + d);            \
            }                                                                \
            __builtin_amdgcn_sched_barrier(0);                               \
            _Pragma("unroll")                                                \
            for (int d = 0; d < 8; ++d) {                                    \
                const hv2 x = as_hv2(sb[cur][d]);                            \
                Aacc[d] = FDOT2(Ea[8 * grp + d], x, Aacc[d]);                \
                Bacc[d] = FDOT2(Eb[8 * grp + d], x, Bacc[d]);                \
            }                                                                \
            __builtin_amdgcn_sched_barrier(0);                               \
        }                                                                    \
        const float sumA = ((Aacc[0] + Aacc[1]) + (Aacc[2] + Aacc[3]))       \
                         + ((Aacc[4] + Aacc[5]) + (Aacc[6] + Aacc[7]));      \
        const float sumB = ((Bacc[0] + Bacc[1]) + (Bacc[2] + Bacc[3]))       \
                         + ((Bacc[4] + Bacc[5]) + (Bacc[6] + Bacc[7]));      \
        w0 = sumA * ehc0;                                                    \
        w1 = sumB * ehc1;                                                    \
        wpk = pk16(w0, w1);                                                  \
        /* off-critical-path: build NEXT step's scale (lag-1, exact pow2) */ \
        CM2 += epend;                                                        \
        float m_ = fmaxf(w0, w1);                                            \
        DPPMAX(m_, 0x111); DPPMAX(m_, 0x112); DPPMAX(m_, 0x114);             \
        DPPMAX(m_, 0x118); DPPMAX(m_, 0x142); DPPMAX(m_, 0x143);             \
        const float mg = __int_as_float(irl(__float_as_int(m_), 63));        \
        const int   e_ = (int)(__float_as_uint(mg) >> 23) - 127;             \
        epend = (float)e_;                                                   \
        const float cn = __int_as_float((127 - e_) << 23);                   \
        ehc0 = exp2f(SNEXT.x * L2E) * cn;                                    \
        ehc1 = exp2f(SNEXT.y * L2E) * cn;                                    \
    }

// One wave per batch element. Lane l owns rows 2l, 2l+1.
// Exponential-space recurrence; lag-1 exact-pow2 rescale; zero LDS.
__global__ __launch_bounds__(64)
__attribute__((amdgpu_waves_per_eu(1, 1)))
void crf_fwd(const float* __restrict__ h,
             const float* __restrict__ trans,
             const int* __restrict__ lengths,
             float* __restrict__ out)
{
    const int b  = blockIdx.x;
    const int l  = threadIdx.x;       // 0..63
    const int r0 = 2 * l, r1 = 2 * l + 1;

    // ---- one-time: E rows r0,r1 as packed f16 pairs over j ----
    hv2 Ea[64], Eb[64];
    {
        const float4* ta = reinterpret_cast<const float4*>(trans + r0 * K_);
        const float4* tb = reinterpret_cast<const float4*>(trans + r1 * K_);
#pragma unroll
        for (int q = 0; q < 32; ++q) {
            float4 x = ta[q];
            Ea[2*q]   = pkh(exp2f(x.x*L2E), exp2f(x.y*L2E));
            Ea[2*q+1] = pkh(exp2f(x.z*L2E), exp2f(x.w*L2E));
            float4 y = tb[q];
            Eb[2*q]   = pkh(exp2f(y.x*L2E), exp2f(y.y*L2E));
            Eb[2*q+1] = pkh(exp2f(y.z*L2E), exp2f(y.w*L2E));
        }
    }

    const int len = lengths[b];
    const float2* hb = reinterpret_cast<const float2*>(h + (size_t)b*(T_*K_) + r0);

    // state: w = scaled exp(score), one-hot at START=127 (lane 63 hi)
    float w0 = 0.0f, w1 = (l == 63) ? 1.0f : 0.0f;
    int   wpk = pk16(w0, w1);
    float CM2 = 0.0f;      // applied log2 scale total
    float epend = 0.0f;    // exponent of the scale baked into current ehc

    float2 s0 = hb[0];
    float2 s1 = hb[(size_t)((1 < len) ? 1 : len - 1) * 64];
    float2 s2 = hb[(size_t)((2 < len) ? 2 : len - 1) * 64];
    float2 s3 = hb[(size_t)((3 < len) ? 3 : len - 1) * 64];
    float ehc0 = exp2f(s0.x * L2E);   // c_0 = 1 (max of init w is 1)
    float ehc1 = exp2f(s0.y * L2E);

    int t = 0;
    const int nfull = len & ~3;
    for (; t < nfull; t += 4) {
        BODY(t+0, s0, s1);
        BODY(t+1, s1, s2);
        BODY(t+2, s2, s3);
        BODY(t+3, s3, s0);
    }
    if (t     < len) BODY(t,   s0, s1);
    if (t + 1 < len) BODY(t+1, s1, s2);
    if (t + 2 < len) BODY(t+2, s2, s3);

    // ---- out[b] = ln2 * (CM2 + log2( sum_i w[i] * exp(trans[END,i]) )) ----
    const float tEa = exp2f(trans[(K_-2)*K_ + r0] * L2E);
    const float tEb = exp2f(trans[(K_-2)*K_ + r1] * L2E);
    float s = w0 * tEa + w1 * tEb;
#pragma unroll
    for (int off = 32; off >= 1; off >>= 1)
        s += __shfl_xor(s, off, 64);
    if (l == 0) out[b] = (CM2 + log2f(s)) * LN2;
}

extern "C" void kernel_launch(void* const* d_in, const int* in_sizes, int n_in,
                              void* d_out, int out_size, void* d_ws, size_t ws_size,
                              hipStream_t stream) {
    const float* h       = (const float*)d_in[0];
    const float* trans   = (const float*)d_in[1];
    const int*   lengths = (const int*)d_in[2];
    float*       out     = (float*)d_out;
    const int B = in_sizes[2];   // 512
    crf_fwd<<<B, 64, 0, stream>>>(h, trans, lengths, out);
}

// Round 12
// 260.197 us; speedup vs baseline: 1.0220x; 1.0220x over previous
//
#include <hip/hip_runtime.h>

#define T_ 512
#define K_ 128
#define L2E 1.4426950408889634f
#define LN2 0.6931471805599453f

typedef _Float16 hv2 __attribute__((ext_vector_type(2)));

__device__ __forceinline__ int irl(int v, int lane) {
    return __builtin_amdgcn_readlane(v, lane);
}
__device__ __forceinline__ hv2 as_hv2(int i) { return __builtin_bit_cast(hv2, i); }
__device__ __forceinline__ hv2 pkh(float a, float b) {
    return __builtin_bit_cast(hv2, __builtin_amdgcn_cvt_pkrtz(a, b));
}
__device__ __forceinline__ int pk16(float a, float b) {
    return __builtin_bit_cast(int, __builtin_amdgcn_cvt_pkrtz(a, b));
}

#if __has_builtin(__builtin_amdgcn_fdot2)
#define FDOT2(a, b, c) __builtin_amdgcn_fdot2((a), (b), (c), false)
#else
__device__ __forceinline__ float fdot2_emu(hv2 a, hv2 b, float c) {
    return fmaf((float)a.x, (float)b.x, fmaf((float)a.y, (float)b.y, c));
}
#define FDOT2(a, b, c) fdot2_emu((a), (b), (c))
#endif

// wave64 max-reduce step via DPP (pure VALU). values >= 0 so 0-fill safe.
#define DPPMAX(m, ctrl)                                                     \
    m = fmaxf(m, __int_as_float(__builtin_amdgcn_update_dpp(                 \
                     0, __float_as_int(m), (ctrl), 0xf, 0xf, true)))

// One step, 4-wave j-split. Each wave: 16 readlane + 32 fdot2 partial matvec
// over its 32-j slice, one ds_write_b64 + raw s_barrier + 4 ds_read_b64
// fixed-order sum (bitwise-identical across waves -> identical state), then
// the lag-1 exact-pow2 rescale tail (identical in every wave).
#define BODY(tt, P, SLOT, SNEXT)                                             \
    {                                                                        \
        const int tc = ((tt) + 4 < len) ? (tt) + 4 : len - 1;                \
        SLOT = hb[(size_t)tc * 64];                                          \
        float Aacc[4] = {0.f, 0.f, 0.f, 0.f};                                \
        float Bacc[4] = {0.f, 0.f, 0.f, 0.f};                                \
        _Pragma("unroll")                                                    \
        for (int d = 0; d < 16; ++d) {                                       \
            const hv2 x = as_hv2(irl(wpk, wbase + d));                       \
            Aacc[d & 3] = FDOT2(Ea[d], x, Aacc[d & 3]);                      \
            Bacc[d & 3] = FDOT2(Eb[d], x, Bacc[d & 3]);                      \
        }                                                                    \
        const float pA = (Aacc[0] + Aacc[1]) + (Aacc[2] + Aacc[3]);          \
        const float pB = (Bacc[0] + Bacc[1]) + (Bacc[2] + Bacc[3]);          \
        *(float2*)&xls[P][w][2 * l] = make_float2(pA, pB);                   \
        asm volatile("s_waitcnt lgkmcnt(0)" ::: "memory");                   \
        __builtin_amdgcn_s_barrier();                                        \
        const float2 x0 = *(const float2*)&xls[P][0][2 * l];                 \
        const float2 x1 = *(const float2*)&xls[P][1][2 * l];                 \
        const float2 x2 = *(const float2*)&xls[P][2][2 * l];                 \
        const float2 x3 = *(const float2*)&xls[P][3][2 * l];                 \
        const float S0 = (x0.x + x1.x) + (x2.x + x3.x);                     \
        const float S1 = (x0.y + x1.y) + (x2.y + x3.y);                     \
        w0 = S0 * ehc0;                                                      \
        w1 = S1 * ehc1;                                                      \
        wpk = pk16(w0, w1);                                                  \
        CM2 += epend;                                                        \
        float m_ = fmaxf(w0, w1);                                            \
        DPPMAX(m_, 0x111); DPPMAX(m_, 0x112); DPPMAX(m_, 0x114);             \
        DPPMAX(m_, 0x118); DPPMAX(m_, 0x142); DPPMAX(m_, 0x143);             \
        const float mg = __int_as_float(irl(__float_as_int(m_), 63));        \
        const int   e_ = (int)(__float_as_uint(mg) >> 23) - 127;             \
        epend = (float)e_;                                                   \
        const float cn = __int_as_float((127 - e_) << 23);                   \
        ehc0 = exp2f(SNEXT.x * L2E) * cn;                                    \
        ehc1 = exp2f(SNEXT.y * L2E) * cn;                                    \
    }

// One block (4 waves) per batch element. Lane l of EVERY wave owns rows
// 2l, 2l+1 (redundant state, bitwise-identical across waves); wave w owns
// the j-slice [32w, 32w+32) of the matvec. Exponential-space recurrence,
// lag-1 exact-pow2 rescale. Raw s_barrier (not __syncthreads) keeps the
// 4-deep h vmcnt prefetch pipeline in flight across steps.
__global__ __launch_bounds__(256)
void crf_fwd(const float* __restrict__ h,
             const float* __restrict__ trans,
             const int* __restrict__ lengths,
             float* __restrict__ out)
{
    const int b   = blockIdx.x;
    const int tid = threadIdx.x;
    const int w   = tid >> 6;        // wave 0..3
    const int l   = tid & 63;        // lane
    const int r0  = 2 * l, r1 = r0 + 1;
    const int jb  = 32 * w;          // this wave's j base
    const int wbase = __builtin_amdgcn_readfirstlane(16 * w);  // readlane base (SGPR)

    __shared__ alignas(16) float xls[2][4][128];   // partials, parity dbuf

    // ---- one-time: E slices, rows r0,r1 x j in [jb, jb+32), packed f16 ----
    hv2 Ea[16], Eb[16];
    {
        const float4* ta = (const float4*)(trans + r0 * K_ + jb);
        const float4* tb = (const float4*)(trans + r1 * K_ + jb);
#pragma unroll
        for (int q = 0; q < 8; ++q) {
            float4 x = ta[q];
            Ea[2*q]   = pkh(exp2f(x.x*L2E), exp2f(x.y*L2E));
            Ea[2*q+1] = pkh(exp2f(x.z*L2E), exp2f(x.w*L2E));
            float4 y = tb[q];
            Eb[2*q]   = pkh(exp2f(y.x*L2E), exp2f(y.y*L2E));
            Eb[2*q+1] = pkh(exp2f(y.z*L2E), exp2f(y.w*L2E));
        }
    }

    const int len = lengths[b];
    const float2* hb = (const float2*)(h + (size_t)b * (T_ * K_) + r0);

    // state: w one-hot at START=127 (lane 63 hi half), identical in all waves
    float w0 = 0.0f, w1 = (l == 63) ? 1.0f : 0.0f;
    int   wpk = pk16(w0, w1);
    float CM2 = 0.0f, epend = 0.0f;

    float2 s0 = hb[0];
    float2 s1 = hb[(size_t)((1 < len) ? 1 : len - 1) * 64];
    float2 s2 = hb[(size_t)((2 < len) ? 2 : len - 1) * 64];
    float2 s3 = hb[(size_t)((3 < len) ? 3 : len - 1) * 64];
    float ehc0 = exp2f(s0.x * L2E);   // c_0 = 1 (max of init w is 1)
    float ehc1 = exp2f(s0.y * L2E);

    int t = 0;
    const int nfull = len & ~3;
    for (; t < nfull; t += 4) {
        BODY(t + 0, 0, s0, s1);
        BODY(t + 1, 1, s1, s2);
        BODY(t + 2, 0, s2, s3);
        BODY(t + 3, 1, s3, s0);
    }
    if (t     < len) BODY(t,     0, s0, s1);
    if (t + 1 < len) BODY(t + 1, 1, s1, s2);
    if (t + 2 < len) BODY(t + 2, 0, s2, s3);

    // ---- out[b] = ln2 * (CM2 + log2( sum_i w[i] * exp(trans[END,i]) )) ----
    // Every wave holds the full final state (lane l: rows 2l,2l+1); wave 0 writes.
    const float tEa = exp2f(trans[(K_ - 2) * K_ + r0] * L2E);
    const float tEb = exp2f(trans[(K_ - 2) * K_ + r1] * L2E);
    float s = w0 * tEa + w1 * tEb;
#pragma unroll
    for (int off = 32; off >= 1; off >>= 1)
        s += __shfl_xor(s, off, 64);
    if (tid == 0) out[b] = (CM2 + log2f(s)) * LN2;
}

extern "C" void kernel_launch(void* const* d_in, const int* in_sizes, int n_in,
                              void* d_out, int out_size, void* d_ws, size_t ws_size,
                              hipStream_t stream) {
    const float* h       = (const float*)d_in[0];
    const float* trans   = (const float*)d_in[1];
    const int*   lengths = (const int*)d_in[2];
    float*       out     = (float*)d_out;
    const int B = in_sizes[2];   // 512
    crf_fwd<<<B, 256, 0, stream>>>(h, trans, lengths, out);
}